// Round 2
// baseline (916.257 us; speedup 1.0000x reference)
//
#include <hip/hip_runtime.h>

typedef unsigned int u32;

#define T_LEN 512
#define BATCH 2048
#define OSTRIDE ((size_t)BATCH * T_LEN * 32)  // 33,554,432 elements per output copy

__device__ __forceinline__ float rlf(float v, int l) {
  return __int_as_float(__builtin_amdgcn_readlane(__float_as_int(v), l));
}
// quad_perm broadcast of quad-lane sel (0..3): ctrl = sel * 0x55
#define QB(v, pat) __int_as_float(__builtin_amdgcn_mov_dpp(__float_as_int(v), (pat), 0xF, 0xF, false))

// ---------------------------------------------------------------------------
// Kernel 1: pre-net.  One thread per (b,t) row: 32 -> 16 -> 16 -> 16.
// Weights staged to LDS once per block; all lanes read the same LDS address
// (broadcast, conflict-free).  x written fp32 to workspace.
// ---------------------------------------------------------------------------
__global__ __launch_bounds__(256) void prenet_kernel(
    const float* __restrict__ seq,
    const float* __restrict__ w1, const float* __restrict__ b1,
    const float* __restrict__ w2, const float* __restrict__ b2,
    const float* __restrict__ w3, const float* __restrict__ b3,
    float* __restrict__ xws) {
  // LDS layout (floats): w1[512]@0, b1[16]@512, w2[256]@528, b2[16]@784,
  //                      w3[256]@800, b3[16]@1056   (all float4-aligned)
  __shared__ float sW[1072];
  const int tid = threadIdx.x;
  sW[tid] = w1[tid];
  sW[256 + tid] = w1[256 + tid];
  sW[528 + tid] = w2[tid];
  sW[800 + tid] = w3[tid];
  if (tid < 16) {
    sW[512 + tid] = b1[tid];
    sW[784 + tid] = b2[tid];
    sW[1056 + tid] = b3[tid];
  }
  __syncthreads();

  const size_t r = (size_t)blockIdx.x * 256 + tid;  // row id, < 1,048,576
  const float* sp = seq + r * 32;

  float in[32];
#pragma unroll
  for (int q = 0; q < 8; ++q) {
    float4 v = ((const float4*)sp)[q];
    in[q * 4 + 0] = v.x;
    in[q * 4 + 1] = v.y;
    in[q * 4 + 2] = v.z;
    in[q * 4 + 3] = v.w;
  }

  const float4* wv = (const float4*)sW;

  float y1[16];
#pragma unroll
  for (int j = 0; j < 16; ++j) {
    float a0 = 0.f, a1 = 0.f, a2 = 0.f, a3 = 0.f;
#pragma unroll
    for (int q = 0; q < 8; ++q) {
      float4 w = wv[j * 8 + q];
      a0 = __builtin_fmaf(w.x, in[q * 4 + 0], a0);
      a1 = __builtin_fmaf(w.y, in[q * 4 + 1], a1);
      a2 = __builtin_fmaf(w.z, in[q * 4 + 2], a2);
      a3 = __builtin_fmaf(w.w, in[q * 4 + 3], a3);
    }
    float s = (a0 + a1) + (a2 + a3) + sW[512 + j];
    y1[j] = s >= 0.f ? s : 0.01f * s;
  }

  float y2[16];
#pragma unroll
  for (int j = 0; j < 16; ++j) {
    float a0 = 0.f, a1 = 0.f, a2 = 0.f, a3 = 0.f;
#pragma unroll
    for (int q = 0; q < 4; ++q) {
      float4 w = wv[132 + j * 4 + q];
      a0 = __builtin_fmaf(w.x, y1[q * 4 + 0], a0);
      a1 = __builtin_fmaf(w.y, y1[q * 4 + 1], a1);
      a2 = __builtin_fmaf(w.z, y1[q * 4 + 2], a2);
      a3 = __builtin_fmaf(w.w, y1[q * 4 + 3], a3);
    }
    float s = (a0 + a1) + (a2 + a3) + sW[784 + j];
    y2[j] = s >= 0.f ? s : 0.01f * s;
  }

  float y3[16];
#pragma unroll
  for (int j = 0; j < 16; ++j) {
    float a0 = 0.f, a1 = 0.f, a2 = 0.f, a3 = 0.f;
#pragma unroll
    for (int q = 0; q < 4; ++q) {
      float4 w = wv[200 + j * 4 + q];
      a0 = __builtin_fmaf(w.x, y2[q * 4 + 0], a0);
      a1 = __builtin_fmaf(w.y, y2[q * 4 + 1], a1);
      a2 = __builtin_fmaf(w.z, y2[q * 4 + 2], a2);
      a3 = __builtin_fmaf(w.w, y2[q * 4 + 3], a3);
    }
    y3[j] = (a0 + a1) + (a2 + a3) + sW[1056 + j];
  }

  float* op = xws + r * 16;
#pragma unroll
  for (int q = 0; q < 4; ++q)
    ((float4*)op)[q] =
        make_float4(y3[q * 4 + 0], y3[q * 4 + 1], y3[q * 4 + 2], y3[q * 4 + 3]);
}

// ---------------------------------------------------------------------------
// Kernel 2: recurrent encoder+decoder.  One wave per batch sample.
// Lane j owns gate gi=(j&3)*16+(j>>2): quad-interleaved so i/f/g/o gather is
// 4 DPP quad_perm broadcasts.  h,c replicated per quad; h broadcast via
// v_readlane into SGPR fmac operands.  x prefetched 4 steps ahead.
// ---------------------------------------------------------------------------
// One fused sigmoid/tanh: e = exp(isTanh ? 2g : -g); r = 1/(1+e);
// sigmoid = r, tanh = 1-2r.
#define CELL(XARR)                                                          \
  do {                                                                      \
    float a0 = bias, a1 = 0.f, a2 = 0.f, a3 = 0.f;                          \
    _Pragma("unroll") for (int k = 0; k < 16; k += 4) {                     \
      a0 = __builtin_fmaf(wihr[k + 0], XARR[k + 0], a0);                    \
      a1 = __builtin_fmaf(wihr[k + 1], XARR[k + 1], a1);                    \
      a2 = __builtin_fmaf(wihr[k + 2], XARR[k + 2], a2);                    \
      a3 = __builtin_fmaf(wihr[k + 3], XARR[k + 3], a3);                    \
    }                                                                       \
    _Pragma("unroll") for (int k = 0; k < 16; k += 4) {                     \
      a0 = __builtin_fmaf(whhr[k + 0], hu[k + 0], a0);                      \
      a1 = __builtin_fmaf(whhr[k + 1], hu[k + 1], a1);                      \
      a2 = __builtin_fmaf(whhr[k + 2], hu[k + 2], a2);                      \
      a3 = __builtin_fmaf(whhr[k + 3], hu[k + 3], a3);                      \
    }                                                                       \
    float g = (a0 + a1) + (a2 + a3);                                        \
    float uu = isT ? (g + g) : (-g);                                        \
    float ee = __expf(uu);                                                  \
    float rr = __builtin_amdgcn_rcpf(1.0f + ee);                            \
    float act = isT ? __builtin_fmaf(-2.0f, rr, 1.0f) : rr;                 \
    float ii = QB(act, 0x00);                                               \
    float ff = QB(act, 0x55);                                               \
    float gg = QB(act, 0xAA);                                               \
    float oo = QB(act, 0xFF);                                               \
    c = __builtin_fmaf(ff, c, ii * gg);                                     \
    float th = __builtin_fmaf(                                              \
        -2.0f, __builtin_amdgcn_rcpf(1.0f + __expf(c + c)), 1.0f);          \
    h = oo * th;                                                            \
    _Pragma("unroll") for (int k = 0; k < 16; ++k) hu[k] = rlf(h, 4 * k);   \
  } while (0)

__global__ __launch_bounds__(256) void lstm_rec_kernel(
    const float* __restrict__ Wih, const float* __restrict__ Whh,
    const float* __restrict__ bih, const float* __restrict__ bhh,
    const float* __restrict__ hw1, const float* __restrict__ hb1,
    const float* __restrict__ hw2, const float* __restrict__ hb2,
    const float* __restrict__ pw, const float* __restrict__ pb,
    const float* __restrict__ xws, float* __restrict__ out) {
  const int lane = threadIdx.x & 63;
  const int b = blockIdx.x * 4 + (threadIdx.x >> 6);  // 0..2047
  const int hr = lane >> 2;                           // h index 0..15 (quad id)
  const int gi = (lane & 3) * 16 + hr;                // gate row 0..63
  const bool isT = (lane & 3) == 2;                   // quad-lane 2 = g gate (tanh)

  float wihr[16], whhr[16];
#pragma unroll
  for (int k = 0; k < 16; ++k) {
    wihr[k] = Wih[gi * 16 + k];
    whhr[k] = Whh[gi * 16 + k];
  }
  const float bias = bih[gi] + bhh[gi];

  float h = 0.f, c = 0.f;
  float hu[16];
#pragma unroll
  for (int k = 0; k < 16; ++k) hu[k] = 0.f;

  const float* xb = xws + (size_t)b * (T_LEN * 16);

  // prefetch ring: rows t..t+3 live in xq[0..3]
  float xq[4][16];
#pragma unroll
  for (int d = 0; d < 4; ++d) {
    const float* src = xb + d * 16;
#pragma unroll
    for (int q = 0; q < 4; ++q) {
      float4 v = ((const float4*)src)[q];
      xq[d][q * 4 + 0] = v.x;
      xq[d][q * 4 + 1] = v.y;
      xq[d][q * 4 + 2] = v.z;
      xq[d][q * 4 + 3] = v.w;
    }
  }

  // ---------------- encoder: 512 steps ----------------
  for (int t0 = 0; t0 < T_LEN; t0 += 4) {
#pragma unroll
    for (int u = 0; u < 4; ++u) {
      CELL(xq[u]);
      // prefetch row t+4 (clamped; harmless reload of row 511 at the tail)
      int tn = t0 + u + 4;
      tn = tn < T_LEN ? tn : (T_LEN - 1);
      const float* src = xb + (size_t)tn * 16;
#pragma unroll
      for (int q = 0; q < 4; ++q) {
        float4 v = ((const float4*)src)[q];
        xq[u][q * 4 + 0] = v.x;
        xq[u][q * 4 + 1] = v.y;
        xq[u][q * 4 + 2] = v.z;
        xq[u][q * 4 + 3] = v.w;
      }
    }
  }

  // decoder-only weights loaded here to keep encoder-phase VGPR pressure low
  float w1r[16], w2r[16], pwr[16];
  const int orow = lane & 31;
#pragma unroll
  for (int k = 0; k < 16; ++k) {
    w1r[k] = hw1[hr * 16 + k];
    w2r[k] = hw2[hr * 16 + k];
    pwr[k] = pw[orow * 16 + k];
  }
  const float b1r = hb1[hr];
  const float b2r = hb2[hr];
  const float pbr = pb[orow];

  // start0 = pre-net output at t = T-1
  float xk[16];
  {
    const float* src = xb + (size_t)(T_LEN - 1) * 16;
#pragma unroll
    for (int q = 0; q < 4; ++q) {
      float4 v = ((const float4*)src)[q];
      xk[q * 4 + 0] = v.x;
      xk[q * 4 + 1] = v.y;
      xk[q * 4 + 2] = v.z;
      xk[q * 4 + 3] = v.w;
    }
  }

  float* out0 = out + ((lane < 32) ? (size_t)0 : OSTRIDE);
  const size_t obase = (size_t)b * (T_LEN * 32) + (lane & 31);

  // ---------------- decoder: 512 steps ----------------
  for (int t = 0; t < T_LEN; ++t) {
    CELL(xk);

    // t1 = leaky(h @ h2l_w1.T + b1)   (replicated per quad, row = hr)
    float p0 = b1r, p1 = 0.f, p2 = 0.f, p3 = 0.f;
#pragma unroll
    for (int k = 0; k < 16; k += 4) {
      p0 = __builtin_fmaf(w1r[k + 0], hu[k + 0], p0);
      p1 = __builtin_fmaf(w1r[k + 1], hu[k + 1], p1);
      p2 = __builtin_fmaf(w1r[k + 2], hu[k + 2], p2);
      p3 = __builtin_fmaf(w1r[k + 3], hu[k + 3], p3);
    }
    float t1s = (p0 + p1) + (p2 + p3);
    float t1v = t1s >= 0.f ? t1s : 0.01f * t1s;
    float t1u[16];
#pragma unroll
    for (int k = 0; k < 16; ++k) t1u[k] = rlf(t1v, 4 * k);

    // start = t1 @ h2l_w2.T + b2
    float q0 = b2r, q1 = 0.f, q2 = 0.f, q3 = 0.f;
#pragma unroll
    for (int k = 0; k < 16; k += 4) {
      q0 = __builtin_fmaf(w2r[k + 0], t1u[k + 0], q0);
      q1 = __builtin_fmaf(w2r[k + 1], t1u[k + 1], q1);
      q2 = __builtin_fmaf(w2r[k + 2], t1u[k + 2], q2);
      q3 = __builtin_fmaf(w2r[k + 3], t1u[k + 3], q3);
    }
    float sv = (q0 + q1) + (q2 + q3);

    // out = h @ post_w.T + post_b   (row = lane&31; lanes 0-31 copy0, 32-63 copy1)
    float o0 = pbr, o1 = 0.f, o2 = 0.f, o3 = 0.f;
#pragma unroll
    for (int k = 0; k < 16; k += 4) {
      o0 = __builtin_fmaf(pwr[k + 0], hu[k + 0], o0);
      o1 = __builtin_fmaf(pwr[k + 1], hu[k + 1], o1);
      o2 = __builtin_fmaf(pwr[k + 2], hu[k + 2], o2);
      o3 = __builtin_fmaf(pwr[k + 3], hu[k + 3], o3);
    }
    float ov = (o0 + o1) + (o2 + o3);

    // next-step input broadcast (uniform)
#pragma unroll
    for (int k = 0; k < 16; ++k) xk[k] = rlf(sv, 4 * k);

    // outputs are time-reversed
    out0[obase + (size_t)(T_LEN - 1 - t) * 32] = ov;
  }
}

extern "C" void kernel_launch(void* const* d_in, const int* in_sizes, int n_in,
                              void* d_out, int out_size, void* d_ws, size_t ws_size,
                              hipStream_t stream) {
  const float* seq = (const float*)d_in[0];
  const float* pre_w1 = (const float*)d_in[1];
  const float* pre_b1 = (const float*)d_in[2];
  const float* pre_w2 = (const float*)d_in[3];
  const float* pre_b2 = (const float*)d_in[4];
  const float* pre_w3 = (const float*)d_in[5];
  const float* pre_b3 = (const float*)d_in[6];
  const float* enc_Wih = (const float*)d_in[7];
  const float* enc_Whh = (const float*)d_in[8];
  const float* enc_bih = (const float*)d_in[9];
  const float* enc_bhh = (const float*)d_in[10];
  const float* h2l_w1 = (const float*)d_in[11];
  const float* h2l_b1 = (const float*)d_in[12];
  const float* h2l_w2 = (const float*)d_in[13];
  const float* h2l_b2 = (const float*)d_in[14];
  const float* post_w = (const float*)d_in[15];
  const float* post_b = (const float*)d_in[16];

  float* xws = (float*)d_ws;  // (B*T, 16) fp32 = 64 MiB

  prenet_kernel<<<dim3(4096), dim3(256), 0, stream>>>(
      seq, pre_w1, pre_b1, pre_w2, pre_b2, pre_w3, pre_b3, xws);

  lstm_rec_kernel<<<dim3(512), dim3(256), 0, stream>>>(
      enc_Wih, enc_Whh, enc_bih, enc_bhh, h2l_w1, h2l_b1, h2l_w2, h2l_b2,
      post_w, post_b, xws, (float*)d_out);
}

// Round 3
// 757.566 us; speedup vs baseline: 1.2095x; 1.2095x over previous
//
#include <hip/hip_runtime.h>

typedef unsigned int u32;
typedef float v2f __attribute__((ext_vector_type(2)));

#define T_LEN 512
#define BATCH 2048
#define OSTRIDE ((size_t)BATCH * T_LEN * 32)  // elements per output copy

__device__ __forceinline__ float rlf(float v, int l) {
  return __int_as_float(__builtin_amdgcn_readlane(__float_as_int(v), l));
}
// quad_perm broadcast of quad-lane sel (0..3): ctrl = sel * 0x55
#define QB(v, pat) __int_as_float(__builtin_amdgcn_mov_dpp(__float_as_int(v), (pat), 0xF, 0xF, false))

// ---------------------------------------------------------------------------
// Kernel 1: pre-net (unchanged from R2 passing version).
// ---------------------------------------------------------------------------
__global__ __launch_bounds__(256) void prenet_kernel(
    const float* __restrict__ seq,
    const float* __restrict__ w1, const float* __restrict__ b1,
    const float* __restrict__ w2, const float* __restrict__ b2,
    const float* __restrict__ w3, const float* __restrict__ b3,
    float* __restrict__ xws) {
  __shared__ float sW[1072];
  const int tid = threadIdx.x;
  sW[tid] = w1[tid];
  sW[256 + tid] = w1[256 + tid];
  sW[528 + tid] = w2[tid];
  sW[800 + tid] = w3[tid];
  if (tid < 16) {
    sW[512 + tid] = b1[tid];
    sW[784 + tid] = b2[tid];
    sW[1056 + tid] = b3[tid];
  }
  __syncthreads();

  const size_t r = (size_t)blockIdx.x * 256 + tid;
  const float* sp = seq + r * 32;

  float in[32];
#pragma unroll
  for (int q = 0; q < 8; ++q) {
    float4 v = ((const float4*)sp)[q];
    in[q * 4 + 0] = v.x;
    in[q * 4 + 1] = v.y;
    in[q * 4 + 2] = v.z;
    in[q * 4 + 3] = v.w;
  }

  const float4* wv = (const float4*)sW;

  float y1[16];
#pragma unroll
  for (int j = 0; j < 16; ++j) {
    float a0 = 0.f, a1 = 0.f, a2 = 0.f, a3 = 0.f;
#pragma unroll
    for (int q = 0; q < 8; ++q) {
      float4 w = wv[j * 8 + q];
      a0 = __builtin_fmaf(w.x, in[q * 4 + 0], a0);
      a1 = __builtin_fmaf(w.y, in[q * 4 + 1], a1);
      a2 = __builtin_fmaf(w.z, in[q * 4 + 2], a2);
      a3 = __builtin_fmaf(w.w, in[q * 4 + 3], a3);
    }
    float s = (a0 + a1) + (a2 + a3) + sW[512 + j];
    y1[j] = s >= 0.f ? s : 0.01f * s;
  }

  float y2[16];
#pragma unroll
  for (int j = 0; j < 16; ++j) {
    float a0 = 0.f, a1 = 0.f, a2 = 0.f, a3 = 0.f;
#pragma unroll
    for (int q = 0; q < 4; ++q) {
      float4 w = wv[132 + j * 4 + q];
      a0 = __builtin_fmaf(w.x, y1[q * 4 + 0], a0);
      a1 = __builtin_fmaf(w.y, y1[q * 4 + 1], a1);
      a2 = __builtin_fmaf(w.z, y1[q * 4 + 2], a2);
      a3 = __builtin_fmaf(w.w, y1[q * 4 + 3], a3);
    }
    float s = (a0 + a1) + (a2 + a3) + sW[784 + j];
    y2[j] = s >= 0.f ? s : 0.01f * s;
  }

  float y3[16];
#pragma unroll
  for (int j = 0; j < 16; ++j) {
    float a0 = 0.f, a1 = 0.f, a2 = 0.f, a3 = 0.f;
#pragma unroll
    for (int q = 0; q < 4; ++q) {
      float4 w = wv[200 + j * 4 + q];
      a0 = __builtin_fmaf(w.x, y2[q * 4 + 0], a0);
      a1 = __builtin_fmaf(w.y, y2[q * 4 + 1], a1);
      a2 = __builtin_fmaf(w.z, y2[q * 4 + 2], a2);
      a3 = __builtin_fmaf(w.w, y2[q * 4 + 3], a3);
    }
    y3[j] = (a0 + a1) + (a2 + a3) + sW[1056 + j];
  }

  float* op = xws + r * 16;
#pragma unroll
  for (int q = 0; q < 4; ++q)
    ((float4*)op)[q] =
        make_float4(y3[q * 4 + 0], y3[q * 4 + 1], y3[q * 4 + 2], y3[q * 4 + 3]);
}

// ---------------------------------------------------------------------------
// Kernel 2: recurrent encoder+decoder.  One wave per batch sample.
// Lane j owns gate gi=(j&3)*16+(j>>2); gate weights PRESCALED by
// sK = isTanh ? 2 : -1 so activation needs no select: e=expf(g');
// rr=rcp(1+e); act=fma(sa,rr,sb).  GEMVs in packed fp32 (v_pk_fma_f32).
// x rows loaded via uniform (scalar) loads.  Decoder fuses post-net and
// h2l_w1 GEMVs across lanes (0-31: post rows, 32-47: w1 rows).
// ---------------------------------------------------------------------------
#define CELL(XP)                                                            \
  do {                                                                      \
    v2f A = {bias, 0.f}, Bv = {0.f, 0.f};                                   \
    _Pragma("unroll") for (int j = 0; j < 8; j += 2) {                      \
      A = __builtin_elementwise_fma(wih2[j], XP[j], A);                     \
      Bv = __builtin_elementwise_fma(wih2[j + 1], XP[j + 1], Bv);           \
    }                                                                       \
    _Pragma("unroll") for (int j = 0; j < 8; j += 2) {                      \
      A = __builtin_elementwise_fma(whh2[j], HU[j], A);                     \
      Bv = __builtin_elementwise_fma(whh2[j + 1], HU[j + 1], Bv);           \
    }                                                                       \
    A = A + Bv;                                                             \
    float g = A.x + A.y; /* prescaled: -graw (sig) or 2*graw (tanh) */      \
    float ee = __expf(g);                                                   \
    float rr = __builtin_amdgcn_rcpf(1.0f + ee);                            \
    float act = __builtin_fmaf(sa, rr, sb);                                 \
    float ii = QB(act, 0x00);                                               \
    float ff = QB(act, 0x55);                                               \
    float gg = QB(act, 0xAA);                                               \
    float oo = QB(act, 0xFF);                                               \
    c = __builtin_fmaf(ff, c, ii * gg);                                     \
    float te = __expf(c + c);                                               \
    float th = __builtin_fmaf(                                              \
        -2.0f, __builtin_amdgcn_rcpf(1.0f + te), 1.0f);                     \
    h = oo * th;                                                            \
    _Pragma("unroll") for (int j = 0; j < 8; ++j) {                         \
      HU[j].x = rlf(h, 8 * j);                                              \
      HU[j].y = rlf(h, 8 * j + 4);                                          \
    }                                                                       \
  } while (0)

__global__ __launch_bounds__(256) void lstm_rec_kernel(
    const float* __restrict__ Wih, const float* __restrict__ Whh,
    const float* __restrict__ bih, const float* __restrict__ bhh,
    const float* __restrict__ hw1, const float* __restrict__ hb1,
    const float* __restrict__ hw2, const float* __restrict__ hb2,
    const float* __restrict__ pw, const float* __restrict__ pb,
    const float* __restrict__ xws, float* __restrict__ out) {
  const int lane = threadIdx.x & 63;
  const int bu =
      __builtin_amdgcn_readfirstlane(blockIdx.x * 4 + (threadIdx.x >> 6));
  const int hr = lane >> 2;             // h index 0..15 (quad id)
  const int gi = (lane & 3) * 16 + hr;  // gate row 0..63
  const bool isT = (lane & 3) == 2;     // quad-lane 2 = g gate (tanh)

  const float sK = isT ? 2.0f : -1.0f;  // gate prescale
  const float sa = isT ? -2.0f : 1.0f;  // act = sa*rr + sb
  const float sb = isT ? 1.0f : 0.0f;

  v2f wih2[8], whh2[8];
#pragma unroll
  for (int j = 0; j < 8; ++j) {
    wih2[j].x = Wih[gi * 16 + 2 * j] * sK;
    wih2[j].y = Wih[gi * 16 + 2 * j + 1] * sK;
    whh2[j].x = Whh[gi * 16 + 2 * j] * sK;
    whh2[j].y = Whh[gi * 16 + 2 * j + 1] * sK;
  }
  const float bias = (bih[gi] + bhh[gi]) * sK;

  float h = 0.f, c = 0.f;
  v2f HU[8];
#pragma unroll
  for (int j = 0; j < 8; ++j) HU[j] = (v2f){0.f, 0.f};

  const float* xb = xws + (size_t)bu * (T_LEN * 16);  // uniform pointer

  // ---------------- encoder: 512 steps, x via scalar loads ----------------
  v2f xs0[8], xs1[8];
#pragma unroll
  for (int j = 0; j < 8; ++j) {
    xs0[j].x = xb[2 * j];
    xs0[j].y = xb[2 * j + 1];
  }
  for (int t = 0; t < T_LEN; t += 2) {
    const float* n1 = xb + (size_t)(t + 1) * 16;
#pragma unroll
    for (int j = 0; j < 8; ++j) {
      xs1[j].x = n1[2 * j];
      xs1[j].y = n1[2 * j + 1];
    }
    CELL(xs0);
    const int t2 = (t + 2 < T_LEN) ? (t + 2) : (T_LEN - 1);
    const float* n2 = xb + (size_t)t2 * 16;
#pragma unroll
    for (int j = 0; j < 8; ++j) {
      xs0[j].x = n2[2 * j];
      xs0[j].y = n2[2 * j + 1];
    }
    CELL(xs1);
  }

  // ---------------- decoder weights ----------------
  // Lanes 0..31: post_w row = lane (out).  Lanes 32..63: h2l_w1 row = lane&15.
  v2f mr2[8], w22[8];
  const int mrow = (lane < 32) ? lane : (lane & 15);
  const float* msrc = (lane < 32) ? (pw + mrow * 16) : (hw1 + mrow * 16);
  const float mbias = (lane < 32) ? pb[mrow] : hb1[mrow];
  const float sl = (lane < 32) ? 1.0f : 0.01f;  // leaky only on w1 lanes
  const int w2row = lane & 15;
#pragma unroll
  for (int j = 0; j < 8; ++j) {
    mr2[j].x = msrc[2 * j];
    mr2[j].y = msrc[2 * j + 1];
    w22[j].x = hw2[w2row * 16 + 2 * j];
    w22[j].y = hw2[w2row * 16 + 2 * j + 1];
  }
  const float b2r = hb2[w2row];

  // start0 = pre-net output at t = T-1 (uniform loads)
  v2f XK[8];
  {
    const float* src = xb + (size_t)(T_LEN - 1) * 16;
#pragma unroll
    for (int j = 0; j < 8; ++j) {
      XK[j].x = src[2 * j];
      XK[j].y = src[2 * j + 1];
    }
  }

  const size_t obase = (size_t)bu * (T_LEN * 32) + (lane & 31);

  // ---------------- decoder: 512 steps ----------------
  for (int t = 0; t < T_LEN; ++t) {
    CELL(XK);

    // fused GEMV: lanes 0-31 -> out rows, lanes 32-47 -> t1 rows (48-63 dup)
    v2f A = {mbias, 0.f}, Bv = {0.f, 0.f};
#pragma unroll
    for (int j = 0; j < 8; j += 2) {
      A = __builtin_elementwise_fma(mr2[j], HU[j], A);
      Bv = __builtin_elementwise_fma(mr2[j + 1], HU[j + 1], Bv);
    }
    A = A + Bv;
    float y0 = A.x + A.y;
    float yv = fmaxf(y0, y0 * sl);  // leaky where sl=0.01, identity where sl=1

    // t1 broadcast from lanes 32..47
    v2f TU[8];
#pragma unroll
    for (int j = 0; j < 8; ++j) {
      TU[j].x = rlf(yv, 32 + 2 * j);
      TU[j].y = rlf(yv, 33 + 2 * j);
    }

    // start = t1 @ h2l_w2.T + b2 (row = lane&15; valid on lanes 0..15)
    v2f C2 = {b2r, 0.f}, D2 = {0.f, 0.f};
#pragma unroll
    for (int j = 0; j < 8; j += 2) {
      C2 = __builtin_elementwise_fma(w22[j], TU[j], C2);
      D2 = __builtin_elementwise_fma(w22[j + 1], TU[j + 1], D2);
    }
    C2 = C2 + D2;
    float sv = C2.x + C2.y;

    // next-step input broadcast from lanes 0..15
#pragma unroll
    for (int j = 0; j < 8; ++j) {
      XK[j].x = rlf(sv, 2 * j);
      XK[j].y = rlf(sv, 2 * j + 1);
    }

    // outputs time-reversed; exec-masked store (lanes 0..31 hold out rows)
    if (lane < 32) {
      const size_t off = obase + (size_t)(T_LEN - 1 - t) * 32;
      out[off] = yv;
      out[off + OSTRIDE] = yv;
    }
  }
}

extern "C" void kernel_launch(void* const* d_in, const int* in_sizes, int n_in,
                              void* d_out, int out_size, void* d_ws, size_t ws_size,
                              hipStream_t stream) {
  const float* seq = (const float*)d_in[0];
  const float* pre_w1 = (const float*)d_in[1];
  const float* pre_b1 = (const float*)d_in[2];
  const float* pre_w2 = (const float*)d_in[3];
  const float* pre_b2 = (const float*)d_in[4];
  const float* pre_w3 = (const float*)d_in[5];
  const float* pre_b3 = (const float*)d_in[6];
  const float* enc_Wih = (const float*)d_in[7];
  const float* enc_Whh = (const float*)d_in[8];
  const float* enc_bih = (const float*)d_in[9];
  const float* enc_bhh = (const float*)d_in[10];
  const float* h2l_w1 = (const float*)d_in[11];
  const float* h2l_b1 = (const float*)d_in[12];
  const float* h2l_w2 = (const float*)d_in[13];
  const float* h2l_b2 = (const float*)d_in[14];
  const float* post_w = (const float*)d_in[15];
  const float* post_b = (const float*)d_in[16];

  float* xws = (float*)d_ws;  // (B*T, 16) fp32 = 64 MiB

  prenet_kernel<<<dim3(4096), dim3(256), 0, stream>>>(
      seq, pre_w1, pre_b1, pre_w2, pre_b2, pre_w3, pre_b3, xws);

  lstm_rec_kernel<<<dim3(512), dim3(256), 0, stream>>>(
      enc_Wih, enc_Whh, enc_bih, enc_bhh, h2l_w1, h2l_b1, h2l_w2, h2l_b2,
      post_w, post_b, xws, (float*)d_out);
}